// Round 8
// baseline (102.584 us; speedup 1.0000x reference)
//
#include <hip/hip_runtime.h>
#include <hip/hip_bf16.h>

typedef unsigned short ushort_t;
typedef unsigned int uint_t;
typedef __attribute__((ext_vector_type(8))) short short8;
typedef __attribute__((ext_vector_type(4))) float f32x4;

#define NEG_VAL -1e10f

#define GL16(gp, lp) __builtin_amdgcn_global_load_lds( \
    (const __attribute__((address_space(1))) uint_t*)(gp), \
    (__attribute__((address_space(3))) uint_t*)(lp), 16, 0, 0)

__device__ __forceinline__ ushort_t f2bf(float x) {
    uint_t u = __float_as_uint(x);
    uint_t r = (u + 0x7fffu + ((u >> 16) & 1u)) >> 16;
    return (ushort_t)r;
}

__device__ __forceinline__ uint_t pkbf(float a, float b) {
    return (uint_t)f2bf(a) | ((uint_t)f2bf(b) << 16);
}

// single-instruction packed fp32x2 -> bf16x2 (RNE), dst.lo = a, dst.hi = b
__device__ __forceinline__ uint_t cvtpk(float a, float b) {
    uint_t r;
    asm("v_cvt_pk_bf16_f32 %0, %1, %2" : "=v"(r) : "v"(a), "v"(b));
    return r;
}

__device__ __forceinline__ float tanh_fast(float x) {
    float e = __expf(2.0f * x);
    return 1.0f - 2.0f / (e + 1.0f);
}

// attn_w[:, 512:1024] (f32 [512][1024]) -> w2 bf16 [512][512]
__global__ void w2conv_kernel(const float* __restrict__ attn_w, ushort_t* __restrict__ w2) {
    int gid = blockIdx.x * 256 + threadIdx.x;  // 65536 quads
    int h = gid >> 7, q = gid & 127;
    float4 v = *(const float4*)(attn_w + (size_t)h * 1024 + 512 + q * 4);
    uint2 p;
    p.x = pkbf(v.x, v.y);
    p.y = pkbf(v.z, v.w);
    *(uint2*)(w2 + h * 512 + q * 4) = p;
}

// hb[b][h] = attn_b[h] + sum_k hidden[b,k] * attn_w[h,k]   (fp32 exact)
__global__ void hproj_kernel(const float* __restrict__ hidden,
                             const float* __restrict__ attn_w,
                             const float* __restrict__ attn_b,
                             float* __restrict__ hb) {
    int gid = blockIdx.x * 256 + threadIdx.x;  // 32768
    int b = gid >> 9, h = gid & 511;
    const float4* hp = (const float4*)(hidden + (size_t)b * 512);
    const float4* wp = (const float4*)(attn_w + (size_t)h * 1024);
    float a0 = 0.f, a1 = 0.f, a2 = 0.f, a3 = 0.f;
    #pragma unroll 4
    for (int i = 0; i < 128; i += 4) {
        float4 x0 = hp[i + 0], w0 = wp[i + 0];
        a0 += x0.x * w0.x + x0.y * w0.y + x0.z * w0.z + x0.w * w0.w;
        float4 x1 = hp[i + 1], w1 = wp[i + 1];
        a1 += x1.x * w1.x + x1.y * w1.y + x1.z * w1.z + x1.w * w1.w;
        float4 x2 = hp[i + 2], w2v = wp[i + 2];
        a2 += x2.x * w2v.x + x2.y * w2v.y + x2.z * w2v.z + x2.w * w2v.w;
        float4 x3 = hp[i + 3], w3 = wp[i + 3];
        a3 += x3.x * w3.x + x3.y * w3.y + x3.z * w3.z + x3.w * w3.w;
    }
    hb[gid] = attn_b[h] + ((a0 + a1) + (a2 + a3));
}

// GEMM: 256(M) x 256(N=h) per block, BK=32, ring-3 LDS, depth-2 prefetch,
// ONE raw barrier + counted vmcnt(6) per k-step. 8 waves (2M x 4N).
// A fp32 in LDS (cvt_pk on read). Epilogue reduces 256 h -> part[nt].
__global__ __launch_bounds__(512, 2) void gemm_kernel(
    const float* __restrict__ enc,      // [65536][512] f32 (row = s*64+b)
    const ushort_t* __restrict__ w2,    // [512][512] bf16
    const float* __restrict__ hb,       // [64][512] f32
    const float* __restrict__ vw,       // [512] f32
    float* __restrict__ part)           // [2][65536] f32
{
    __shared__ __align__(16) float As[3][256 * 32];      // 32 KB x3 fp32
    __shared__ __align__(16) ushort_t Bs[3][256 * 32];   // 16 KB x3 bf16
    __shared__ float red[4][256];                         // 4 KB

    const int tid = threadIdx.x;
    const int bid = blockIdx.x;
    // bijective XCD swizzle (512 = 8 x 64): both nt of one mt adjacent on one XCD
    const int xcd = bid & 7, j = bid >> 3;
    const int mt = xcd * 32 + (j >> 1), nt = j & 1;
    const size_t m0 = (size_t)mt * 256;
    const int h0 = nt * 256;

    const int wv = tid >> 6, l = tid & 63;
    const int wm = wv >> 2, wn = wv & 3;
    const int lr = l & 15, lq = l >> 4;

    // ---- A staging: 4 gloads/thread. unit u = i*512 + tid (16B units)
    // row = u>>3, slot p = tid&7, pre-swizzled source unit j = p ^ (row&7)
    const float* aG[4];
    uint_t aL[4];
    #pragma unroll
    for (int i = 0; i < 4; i++) {
        int row = i * 64 + (tid >> 3);
        int jj = (tid & 7) ^ ((tid >> 3) & 7);
        aG[i] = enc + (m0 + row) * 512 + jj * 4;
        aL[i] = (uint_t)(i * 512 + wv * 64) * 16;   // wave-uniform byte base
    }
    // ---- B staging: 2 gloads/thread. unit u = i*512 + tid
    // row = u>>2, slot p = tid&3, source unit j = p ^ ((row>>1)&3)
    const ushort_t* bG[2];
    uint_t bL[2];
    #pragma unroll
    for (int i = 0; i < 2; i++) {
        int row = i * 128 + (tid >> 2);
        int jj = (tid & 3) ^ ((tid >> 3) & 3);
        bG[i] = w2 + (size_t)(h0 + row) * 512 + jj * 8;
        bL[i] = (uint_t)(i * 512 + wv * 64) * 16;
    }

    // ---- fragment read byte-offsets (inverse of same involutions) ----
    uint_t aoff0[8], aoff1[8], boff[4];
    #pragma unroll
    for (int mf = 0; mf < 8; mf++) {
        int r = wm * 128 + mf * 16 + lr;
        aoff0[mf] = (uint_t)r * 128 + (uint_t)(((lq * 2 + 0) ^ (r & 7)) * 16);
        aoff1[mf] = (uint_t)r * 128 + (uint_t)(((lq * 2 + 1) ^ (r & 7)) * 16);
    }
    #pragma unroll
    for (int nf = 0; nf < 4; nf++) {
        int r = wn * 64 + nf * 16 + lr;
        boff[nf] = (uint_t)r * 64 + (uint_t)((lq ^ ((r >> 1) & 3)) * 16);
    }

    #define STAGE_A(kt, buf) do { \
        _Pragma("unroll") \
        for (int i = 0; i < 4; i++) GL16(aG[i] + (kt) * 32, (char*)(&As[(buf)][0]) + aL[i]); \
    } while (0)
    #define STAGE_B(kt, buf) do { \
        _Pragma("unroll") \
        for (int i = 0; i < 2; i++) GL16(bG[i] + (kt) * 32, (char*)(&Bs[(buf)][0]) + bL[i]); \
    } while (0)

    // prologue: depth-2 tile prefetch (6 gloads per wave per tile)
    STAGE_A(0, 0); STAGE_B(0, 0);
    STAGE_A(1, 1); STAGE_B(1, 1);

    f32x4 acc[8][4] = {};

    #pragma unroll
    for (int kt = 0; kt < 16; ++kt) {
        const int cur = kt % 3;
        // gate: own tile-kt loads done (tile kt+1's 6 may stay in flight)
        if (kt < 15) { asm volatile("s_waitcnt vmcnt(6)" ::: "memory"); }
        else         { asm volatile("s_waitcnt vmcnt(0)" ::: "memory"); }
        __builtin_amdgcn_s_barrier();   // => ALL waves' tile-kt loads landed
        asm volatile("" ::: "memory");  // no LDS access hoists above barrier

        if (kt + 2 <= 15) STAGE_A(kt + 2, (kt + 2) % 3);

        short8 bfr[4];
        #pragma unroll
        for (int nf = 0; nf < 4; nf++)
            bfr[nf] = *(const short8*)((const char*)(&Bs[cur][0]) + boff[nf]);

        short8 af[4];
        #pragma unroll
        for (int mf = 0; mf < 4; mf++) {
            f32x4 lo = *(const f32x4*)((const char*)(&As[cur][0]) + aoff0[mf]);
            f32x4 hi = *(const f32x4*)((const char*)(&As[cur][0]) + aoff1[mf]);
            union { short8 s; uint_t u[4]; } t;
            t.u[0] = cvtpk(lo[0], lo[1]);
            t.u[1] = cvtpk(lo[2], lo[3]);
            t.u[2] = cvtpk(hi[0], hi[1]);
            t.u[3] = cvtpk(hi[2], hi[3]);
            af[mf] = t.s;
        }
        __builtin_amdgcn_s_setprio(1);
        #pragma unroll
        for (int mf = 0; mf < 4; mf++)
            #pragma unroll
            for (int nf = 0; nf < 4; nf++)
                acc[mf][nf] = __builtin_amdgcn_mfma_f32_16x16x32_bf16(af[mf], bfr[nf], acc[mf][nf], 0, 0, 0);
        __builtin_amdgcn_s_setprio(0);

        if (kt + 2 <= 15) STAGE_B(kt + 2, (kt + 2) % 3);

        short8 ag[4];
        #pragma unroll
        for (int mf = 0; mf < 4; mf++) {
            f32x4 lo = *(const f32x4*)((const char*)(&As[cur][0]) + aoff0[mf + 4]);
            f32x4 hi = *(const f32x4*)((const char*)(&As[cur][0]) + aoff1[mf + 4]);
            union { short8 s; uint_t u[4]; } t;
            t.u[0] = cvtpk(lo[0], lo[1]);
            t.u[1] = cvtpk(lo[2], lo[3]);
            t.u[2] = cvtpk(hi[0], hi[1]);
            t.u[3] = cvtpk(hi[2], hi[3]);
            ag[mf] = t.s;
        }
        __builtin_amdgcn_s_setprio(1);
        #pragma unroll
        for (int mf = 0; mf < 4; mf++)
            #pragma unroll
            for (int nf = 0; nf < 4; nf++)
                acc[mf + 4][nf] = __builtin_amdgcn_mfma_f32_16x16x32_bf16(ag[mf], bfr[nf], acc[mf + 4][nf], 0, 0, 0);
        __builtin_amdgcn_s_setprio(0);
    }
    #undef STAGE_A
    #undef STAGE_B

    // ---- epilogue: tanh(pre + hb) * v, reduce over this block's 256 h ----
    float vv[4];
    #pragma unroll
    for (int nf = 0; nf < 4; nf++) vv[nf] = vw[h0 + wn * 64 + nf * 16 + lr];

    #pragma unroll
    for (int mf = 0; mf < 8; mf++) {
        #pragma unroll
        for (int r = 0; r < 4; r++) {
            int row = wm * 128 + mf * 16 + lq * 4 + r;   // 0..255
            int b = row & 63;
            const float* hbp = hb + b * 512 + h0 + wn * 64 + lr;
            float p = 0.f;
            #pragma unroll
            for (int nf = 0; nf < 4; nf++) {
                float x = acc[mf][nf][r] + hbp[nf * 16];
                p += tanh_fast(x) * vv[nf];
            }
            p += __shfl_xor(p, 1);
            p += __shfl_xor(p, 2);
            p += __shfl_xor(p, 4);
            p += __shfl_xor(p, 8);
            if (lr == 0) red[wn][row] = p;
        }
    }
    __syncthreads();
    if (tid < 256) {
        part[(size_t)nt * 65536 + m0 + tid] =
            (red[0][tid] + red[1][tid]) + (red[2][tid] + red[3][tid]);
    }
}

// Masked softmax over s for each b. part layout [2][s*64+b], out [b][s].
__global__ void softmax_kernel(const float* __restrict__ part,
                               const int* __restrict__ mask,
                               float* __restrict__ out) {
    __shared__ float sred[8];
    int b = blockIdx.x;
    int t = threadIdx.x;  // 256
    float vals[4];
    float mx = -INFINITY;
    #pragma unroll
    for (int i = 0; i < 4; i++) {
        int s = t + i * 256;
        int row = s * 64 + b;
        float x = part[row] + part[65536 + row];
        if (mask[b * 1024 + s] == 0) x = NEG_VAL;
        vals[i] = x;
        mx = fmaxf(mx, x);
    }
    #pragma unroll
    for (int o = 32; o; o >>= 1) mx = fmaxf(mx, __shfl_xor(mx, o));
    int w = t >> 6;
    if ((t & 63) == 0) sred[w] = mx;
    __syncthreads();
    mx = fmaxf(fmaxf(sred[0], sred[1]), fmaxf(sred[2], sred[3]));
    float sum = 0.f;
    #pragma unroll
    for (int i = 0; i < 4; i++) {
        vals[i] = __expf(vals[i] - mx);
        sum += vals[i];
    }
    #pragma unroll
    for (int o = 32; o; o >>= 1) sum += __shfl_xor(sum, o);
    if ((t & 63) == 0) sred[4 + w] = sum;
    __syncthreads();
    float tot = (sred[4] + sred[5]) + (sred[6] + sred[7]);
    float inv = 1.0f / tot;
    #pragma unroll
    for (int i = 0; i < 4; i++) out[b * 1024 + t + i * 256] = vals[i] * inv;
}

extern "C" void kernel_launch(void* const* d_in, const int* in_sizes, int n_in,
                              void* d_out, int out_size, void* d_ws, size_t ws_size,
                              hipStream_t stream) {
    const float* hidden = (const float*)d_in[1];
    const float* enc    = (const float*)d_in[2];
    const int*   mask   = (const int*)d_in[3];
    const float* attn_w = (const float*)d_in[9];
    const float* attn_b = (const float*)d_in[10];
    const float* vw     = (const float*)d_in[11];
    float* out = (float*)d_out;

    char* ws = (char*)d_ws;
    ushort_t* w2 = (ushort_t*)ws;                    // 512 KB
    float* hb   = (float*)(ws + 512 * 1024);         // 128 KB
    float* part = (float*)(ws + 640 * 1024);         // 512 KB (2 x 65536 f32)

    w2conv_kernel<<<256, 256, 0, stream>>>(attn_w, w2);
    hproj_kernel<<<128, 256, 0, stream>>>(hidden, attn_w, attn_b, hb);
    gemm_kernel<<<512, 512, 0, stream>>>(enc, w2, hb, vw, part);
    softmax_kernel<<<64, 256, 0, stream>>>(part, mask, out);
}